// Round 14
// baseline (168.092 us; speedup 1.0000x reference)
//
#include <hip/hip_runtime.h>
#include <math.h>

// ---------------------------------------------------------------------------
// StatePerturbationEncoder, R22: single fused kernel (prep folded into
// phase 0) + R19/R21 core.
//  R21 post-mortem: dur_us reproduces at 160.0/160.6 (noise +-0.6us) but
//  rocprof dispatch timing swings 30% run-to-run -> only dur_us is
//  trustworthy. Remaining removable term: prep dispatch + gap (~8-10us
//  serialized ahead of fused).
//  R22: phase 0 inside fused_enc transposes W -> Wt and zeroes stats using
//  AGENT-scope stores (coherence-point deposit, R16-validated); the L1
//  pre-K grid barrier (4th phase) orders them against all blocks' normal
//  Wt loads (dispatch-start acquire leaves L2 clean of stale ws lines --
//  the same property prep->fused relied on since R12). L1's barrier sits
//  AFTER gather staging so staging overlaps phase-0 skew. Barrier region
//  zeroed by captured hipMemsetAsync (R11-validated).
//  Core layers byte-identical to R19/R21 (proven 160.0us, absmax 0.0234).
// ---------------------------------------------------------------------------

typedef __attribute__((ext_vector_type(8))) short short8;   // 8 x bf16
typedef __attribute__((ext_vector_type(4))) float floatx4;  // MFMA acc

#define DDIM 256
#define NBLK 512

struct Params {
    const int* ids;
    const float* table;
    const float* W[4];
    const float* b[4];
    const float* g[3];
    const float* be[3];
    unsigned short* Wt;        // ws: 4 * 65536 bf16 (filled by phase 0)
    float* stats;              // ws: 3 layers x 4096 f32 (8 shards x 512)
    unsigned int* barrier;     // ws: 4KB (4 phases x 256 uints), memset 0
    float* out;                // d_out f32
};

__device__ __forceinline__ unsigned short f2bf(float f) {
    union { float f; unsigned int u; } v; v.f = f;
    unsigned int r = v.u + 0x7fffu + ((v.u >> 16) & 1u);   // RNE
    return (unsigned short)(r >> 16);
}
__device__ __forceinline__ float bf2f(unsigned short u) {
    union { unsigned int i; float f; } v; v.i = ((unsigned int)u) << 16;
    return v.f;
}
__device__ __forceinline__ float gelu_fast(float x) {
    // tanh-approx GELU, branchless (validated: absmax 0.023 vs 0.076 thr)
    float z = 0.7978845608f * (x + 0.044715f * x * x * x);
    float e = __expf(2.0f * z);
    float th = 1.0f - 2.0f * __builtin_amdgcn_rcpf(1.0f + e);
    return 0.5f * x * (1.0f + th);
}

// ---------------------------------------------------------------------------
// Grid barrier, tree-arrival (R15-proven): 8 group counters on separate 64B
// lines -> root -> flag; pollers read only the flag with s_sleep(8) backoff.
// Bounded spin: deadlock -> wrong answer, never a hang.
// Phase layout (256 uints): grp g at [g*16], root at [128], flag at [192].
// ---------------------------------------------------------------------------
__device__ __forceinline__ void grid_barrier(unsigned int* base, int phase)
{
    unsigned int* ph = base + phase * 256;
    __syncthreads();   // s_waitcnt vmcnt(0) lgkmcnt(0) + s_barrier (all waves)
    if (threadIdx.x == 0) {
        asm volatile("s_waitcnt vmcnt(0)" ::: "memory");
        unsigned int* gc   = ph + (blockIdx.x >> 6) * 16;   // 8 groups x 64
        unsigned int* root = ph + 128;
        unsigned int* flag = ph + 192;
        bool done = false;
        unsigned int old = __hip_atomic_fetch_add(gc, 1u, __ATOMIC_RELAXED,
                                                  __HIP_MEMORY_SCOPE_AGENT);
        if (old == 63u) {
            unsigned int r = __hip_atomic_fetch_add(root, 1u, __ATOMIC_RELAXED,
                                                    __HIP_MEMORY_SCOPE_AGENT);
            if (r == 7u) {
                __hip_atomic_store(flag, 1u, __ATOMIC_RELAXED,
                                   __HIP_MEMORY_SCOPE_AGENT);
                done = true;
            }
        }
        if (!done) {
            int cap = 2000000;
            while (!__hip_atomic_load(flag, __ATOMIC_RELAXED,
                                      __HIP_MEMORY_SCOPE_AGENT)) {
                __builtin_amdgcn_s_sleep(8);
                if (--cap == 0) break;
            }
        }
    }
    __syncthreads();
}

// ---------------------------------------------------------------------------
// One layer, 8-wave version (R19/R21 core). Block tile 64x256; wave wn owns
// cols wn*32..+31 (acc 4x2 of 16x16x32 MFMAs).
// GATHER: stage A from table; BAR0: grid barrier (phase 0) replaces the
//   A-visibility syncthreads (orders phase-0 Wt agent-stores vs K-loop).
// !GATHER: acc carries y=GELU(prev) across the barrier; finalize stats ->
//   sc/sh, then write AFFINED A panel directly from registers.
// P layout: row r, granule g (8 bf16) at slot g^(r&7) (conflict-free).
// Stats: s1 at statShards[shard*512+col], s2 at +256, shard=blk&7.
// ---------------------------------------------------------------------------
template<int GATHER, int LAST, int BAR0>
__device__ __forceinline__ void layer_step(
    unsigned short* P, float* sc, float* sh,
    const Params& p, floatx4 (&acc)[4][2],
    const unsigned short* Wt, const float* bias,
    const float* statsIn, const float* gma, const float* bta,
    float* statShards)
{
    const int tid  = threadIdx.x;          // 0..511
    const int blk  = blockIdx.x;
    const int wave = tid >> 6;             // 0..7
    const int lane = tid & 63;
    const int quad = lane >> 4;
    const int l15  = lane & 15;
    const int row0 = blk * 64;

    if (GATHER) {
        // ---- stage A from table (thread t: row t>>3, granules (t&7)*4..+3)
        const int r     = tid >> 3;
        const int gbase = (tid & 7) * 4;
        const int src = p.ids[row0 + r];
        const float* tp = p.table + (size_t)src * DDIM + gbase * 8;
#pragma unroll
        for (int j = 0; j < 4; ++j) {
            float4 v0 = *(const float4*)(tp + j * 8);
            float4 v1 = *(const float4*)(tp + j * 8 + 4);
            union { unsigned short u[8]; uint4 v; } o;
            o.u[0]=f2bf(v0.x); o.u[1]=f2bf(v0.y); o.u[2]=f2bf(v0.z); o.u[3]=f2bf(v0.w);
            o.u[4]=f2bf(v1.x); o.u[5]=f2bf(v1.y); o.u[6]=f2bf(v1.z); o.u[7]=f2bf(v1.w);
            const int g = gbase + j;
            *(uint4*)(P + r * 256 + ((g ^ (r & 7)) << 3)) = o.v;
        }
    } else {
        // ---- finalize BN stats of prev layer (threads 0..255 -> col t).
        // AGENT-scope (sc1) loads read at the coherence point (XCD-safe).
        if (tid < 256) {
            float sum = 0.f, sq = 0.f;
#pragma unroll
            for (int s = 0; s < 8; ++s) {
                sum += __hip_atomic_load(&statsIn[s * 512 + tid],
                                         __ATOMIC_RELAXED, __HIP_MEMORY_SCOPE_AGENT);
                sq  += __hip_atomic_load(&statsIn[s * 512 + 256 + tid],
                                         __ATOMIC_RELAXED, __HIP_MEMORY_SCOPE_AGENT);
            }
            const float mu  = sum * (1.f / 32768.f);
            const float var = sq * (1.f / 32768.f) - mu * mu;
            const float scl = rsqrtf(var + 1e-5f) * gma[tid];
            sc[tid] = scl;
            sh[tid] = bta[tid] - mu * scl;
        }
        __syncthreads();   // sc/sh visible before A-writes use them

        // ---- write AFFINED A panel directly from register-carried y ----
#pragma unroll
        for (int mt = 0; mt < 4; ++mt) {
#pragma unroll
            for (int nt = 0; nt < 2; ++nt) {
                const int col = wave * 32 + nt * 16 + l15;
                const float scl = sc[col], shf = sh[col];
                const int gq = col >> 3, c7 = col & 7;
#pragma unroll
                for (int i = 0; i < 4; ++i) {
                    const int r = mt * 16 + quad * 4 + i;
                    const float a = fmaf(acc[mt][nt][i], scl, shf);
                    P[r * 256 + ((gq ^ (r & 7)) << 3) + c7] = f2bf(a);
                }
            }
        }
    }

    float bias_v[2];
#pragma unroll
    for (int nt = 0; nt < 2; ++nt)
        bias_v[nt] = bias[wave * 32 + nt * 16 + l15];

    // A panel visible to all waves; for L1 the grid barrier also orders
    // phase-0 Wt/stats agent-stores against the K-loop's normal loads.
    if (BAR0) grid_barrier(p.barrier, 0);
    else      __syncthreads();

#pragma unroll
    for (int i = 0; i < 4; ++i)
#pragma unroll
        for (int j = 0; j < 2; ++j)
            acc[i][j] = floatx4{0.f, 0.f, 0.f, 0.f};

    // ---- K loop: manual 1-deep pipeline; B from global (L2-hot), A LDS ----
    const unsigned short* wb = Wt + (size_t)(wave * 32 + l15) * DDIM + quad * 8;
    short8 bfr[2], bnx[2], af[4], anx[4];
    {
        const int agp = (quad ^ (l15 & 7)) * 8;               // kk = 0
#pragma unroll
        for (int nt = 0; nt < 2; ++nt)
            bfr[nt] = *(const short8*)(wb + (size_t)(nt * 16) * DDIM);
#pragma unroll
        for (int mt = 0; mt < 4; ++mt)
            af[mt] = *(const short8*)(P + (mt * 16 + l15) * 256 + agp);
    }
#pragma unroll
    for (int kk = 0; kk < 8; ++kk) {
        if (kk < 7) {
            const int agp = (((kk + 1) * 4 + quad) ^ (l15 & 7)) * 8;
#pragma unroll
            for (int nt = 0; nt < 2; ++nt)
                bnx[nt] = *(const short8*)(wb + (size_t)(nt * 16) * DDIM
                                           + (kk + 1) * 32);
#pragma unroll
            for (int mt = 0; mt < 4; ++mt)
                anx[mt] = *(const short8*)(P + (mt * 16 + l15) * 256 + agp);
        }
#pragma unroll
        for (int mt = 0; mt < 4; ++mt)
#pragma unroll
            for (int nt = 0; nt < 2; ++nt)
                acc[mt][nt] = __builtin_amdgcn_mfma_f32_16x16x32_bf16(
                    af[mt], bfr[nt], acc[mt][nt], 0, 0, 0);
#pragma unroll
        for (int x = 0; x < 4; ++x) af[x] = anx[x];
#pragma unroll
        for (int x = 0; x < 2; ++x) bfr[x] = bnx[x];
    }

    // ---- epilogue ----
    if (LAST) {
        // bias + GELU -> global f32 out
#pragma unroll
        for (int mt = 0; mt < 4; ++mt)
#pragma unroll
            for (int nt = 0; nt < 2; ++nt) {
                const int col = wave * 32 + nt * 16 + l15;
#pragma unroll
                for (int i = 0; i < 4; ++i) {
                    const int r = mt * 16 + quad * 4 + i;
                    p.out[(size_t)(row0 + r) * DDIM + col] =
                        gelu_fast(acc[mt][nt][i] + bias_v[nt]);
                }
            }
    } else {
        // bias + GELU -> y kept IN acc (carried across the barrier);
        // column stats -> sharded atomics.
        float s1[2] = {0.f, 0.f};
        float s2[2] = {0.f, 0.f};
#pragma unroll
        for (int mt = 0; mt < 4; ++mt)
#pragma unroll
            for (int nt = 0; nt < 2; ++nt)
#pragma unroll
                for (int i = 0; i < 4; ++i) {
                    const float y = gelu_fast(acc[mt][nt][i] + bias_v[nt]);
                    acc[mt][nt][i] = y;
                    s1[nt] += y; s2[nt] += y * y;
                }
#pragma unroll
        for (int nt = 0; nt < 2; ++nt) {   // reduce the 4 quads (same column)
            s1[nt] += __shfl_xor(s1[nt], 16); s1[nt] += __shfl_xor(s1[nt], 32);
            s2[nt] += __shfl_xor(s2[nt], 16); s2[nt] += __shfl_xor(s2[nt], 32);
        }
        float* sb = statShards + (blk & 7) * 512;            // 8-way shard
        if (quad == 0) {
#pragma unroll
            for (int nt = 0; nt < 2; ++nt) {
                const int col = wave * 32 + nt * 16 + l15;
                atomicAdd(&sb[col],       s1[nt]);
                atomicAdd(&sb[256 + col], s2[nt]);
            }
        }
    }
}

// ---------------------------------------------------------------------------
// Fused kernel: phase0 (Wt transpose + stats zero, agent stores) -> L1..L4.
// grid 512 x 512thr, 34KB static LDS, launch_bounds(512,4).
// ---------------------------------------------------------------------------
__global__ __launch_bounds__(512, 4) void fused_enc(Params p)
{
    __shared__ alignas(16) unsigned short P[64 * 256];   // 32 KB panel
    __shared__ float sc[256], sh[256];                   // 2 KB

    const int tid = threadIdx.x, blk = blockIdx.x;

    // ---- phase 0: one element per thread. id -> W[j][k][n] -> Wt[j][n][k].
    // Reads stride-1KB (L2-absorbed, lines shared by 8 blocks); writes
    // 2B-contiguous per wave. AGENT-scope stores deposit at the coherence
    // point; the L1 pre-K grid barrier orders them vs normal Wt loads.
    {
        const int id  = blk * 512 + tid;            // 0..262143
        const int j   = id >> 16;
        const int rem = id & 65535;
        const int n   = rem >> 8;
        const int k   = rem & 255;
        const unsigned short w = f2bf(p.W[j][(size_t)k * DDIM + n]);
        __hip_atomic_store(&p.Wt[((size_t)j << 16) + (size_t)n * DDIM + k], w,
                           __ATOMIC_RELAXED, __HIP_MEMORY_SCOPE_AGENT);
        if (blk < 48 && tid < 256)                  // zero 3x4096 stat shards
            __hip_atomic_store(&p.stats[blk * 256 + tid], 0.f,
                               __ATOMIC_RELAXED, __HIP_MEMORY_SCOPE_AGENT);
    }

    floatx4 acc[4][2];

    layer_step<1, 0, 1>(P, sc, sh, p, acc, p.Wt,          p.b[0],
                        nullptr,         nullptr, nullptr, p.stats);
    grid_barrier(p.barrier, 1);
    layer_step<0, 0, 0>(P, sc, sh, p, acc, p.Wt + 65536,  p.b[1],
                        p.stats,         p.g[0],  p.be[0], p.stats + 4096);
    grid_barrier(p.barrier, 2);
    layer_step<0, 0, 0>(P, sc, sh, p, acc, p.Wt + 131072, p.b[2],
                        p.stats + 4096,  p.g[1],  p.be[1], p.stats + 8192);
    grid_barrier(p.barrier, 3);
    layer_step<0, 1, 0>(P, sc, sh, p, acc, p.Wt + 196608, p.b[3],
                        p.stats + 8192,  p.g[2],  p.be[2], nullptr);
}

// ---------------------------------------------------------------------------
extern "C" void kernel_launch(void* const* d_in, const int* in_sizes, int n_in,
                              void* d_out, int out_size, void* d_ws, size_t ws_size,
                              hipStream_t stream)
{
    Params pp;
    pp.ids   = (const int*)  d_in[0];
    pp.table = (const float*)d_in[1];
    pp.W[0] = (const float*)d_in[2];  pp.b[0] = (const float*)d_in[3];
    pp.W[1] = (const float*)d_in[4];  pp.b[1] = (const float*)d_in[5];
    pp.W[2] = (const float*)d_in[6];  pp.b[2] = (const float*)d_in[7];
    pp.W[3] = (const float*)d_in[8];  pp.b[3] = (const float*)d_in[9];
    pp.g[0] = (const float*)d_in[10]; pp.be[0] = (const float*)d_in[11];
    pp.g[1] = (const float*)d_in[12]; pp.be[1] = (const float*)d_in[13];
    pp.g[2] = (const float*)d_in[14]; pp.be[2] = (const float*)d_in[15];

    unsigned char* ws = (unsigned char*)d_ws;
    pp.Wt      = (unsigned short*)ws;                          // 512 KiB
    pp.stats   = (float*)(ws + (size_t)524288);                // 48 KiB
    pp.barrier = (unsigned int*)(ws + (size_t)589824);         // 4 KiB
    pp.out     = (float*)d_out;

    // zero the 4-phase barrier region (graph-capturable, R11-validated)
    hipMemsetAsync(ws + (size_t)589824, 0, 4096, stream);

    fused_enc<<<dim3(NBLK), dim3(512), 0, stream>>>(pp);
}

// Round 15
// 160.128 us; speedup vs baseline: 1.0497x; 1.0497x over previous
//
#include <hip/hip_runtime.h>
#include <math.h>

// ---------------------------------------------------------------------------
// StatePerturbationEncoder, R23: REVERT to R21/R19 (best proven: 160.0 /
// 160.6 us dur, twice reproduced).
//  R22 post-mortem: folding prep into fused phase-0 regressed dur 160.6->
//  168.1 (FETCH +4MB from stride-1KB W over-fetch, + extra grid barrier +
//  phase-0 work in-kernel > prep dispatch cost). Theory falsified; the
//  two-dispatch split was already right.
//  Session ledger: wins = fused-single-kernel w/ light barrier (R12),
//  8-wave occupancy (R13), decontended flag poll (R14), tree arrival
//  (R15), register-carried activations (R19). Five structural
//  perturbations of this balance failed (R16/R17/R18/R20/R22) -> narrow
//  local optimum; terminal state = validated best kernel.
// ---------------------------------------------------------------------------

typedef __attribute__((ext_vector_type(8))) short short8;   // 8 x bf16
typedef __attribute__((ext_vector_type(4))) float floatx4;  // MFMA acc

#define DDIM 256
#define NBLK 512

struct Params {
    const int* ids;
    const float* table;
    const float* b[4];
    const float* g[3];
    const float* be[3];
    const unsigned short* Wt;  // ws: 4 * 65536 bf16 (filled by prep)
    float* stats;              // ws: 3 layers x 4096 f32 (8 shards x 512)
    unsigned int* barrier;     // ws: 4KB region (3 phases x 256 uints used)
    float* out;                // d_out f32
};

__device__ __forceinline__ unsigned short f2bf(float f) {
    union { float f; unsigned int u; } v; v.f = f;
    unsigned int r = v.u + 0x7fffu + ((v.u >> 16) & 1u);   // RNE
    return (unsigned short)(r >> 16);
}
__device__ __forceinline__ float bf2f(unsigned short u) {
    union { unsigned int i; float f; } v; v.i = ((unsigned int)u) << 16;
    return v.f;
}
__device__ __forceinline__ float gelu_fast(float x) {
    // tanh-approx GELU, branchless (validated: absmax 0.023 vs 0.076 thr)
    float z = 0.7978845608f * (x + 0.044715f * x * x * x);
    float e = __expf(2.0f * z);
    float th = 1.0f - 2.0f * __builtin_amdgcn_rcpf(1.0f + e);
    return 0.5f * x * (1.0f + th);
}

// ---------------------------------------------------------------------------
// K0: LDS-tiled transpose+cast W -> Wt (bf16 [n][k]); zero stats + barrier.
// 64 blocks: block b -> W[b>>4], 64x64 tile (b&15). (R15-proven verbatim.)
// ---------------------------------------------------------------------------
__global__ __launch_bounds__(256) void prep_kernel(
    const float* __restrict__ W0, const float* __restrict__ W1,
    const float* __restrict__ W2, const float* __restrict__ W3,
    unsigned short* __restrict__ Wt, float* __restrict__ stats,
    unsigned int* __restrict__ barrier)
{
    __shared__ unsigned short T[64][68];
    const int t = threadIdx.x, b = blockIdx.x;     // 64 blocks x 256 thr
    const int j  = b >> 4;
    const int kr = ((b >> 2) & 3) * 64;            // k (row of W) base
    const int nc = (b & 3) * 64;                   // n (col of W) base
    const float* W = (j == 0) ? W0 : (j == 1) ? W1 : (j == 2) ? W2 : W3;

    {   // load: thread t -> k = kr+(t>>2), cols nc+(t&3)*16 .. +15
        const int k = t >> 2, c0 = (t & 3) * 16;
        const float* src = W + (size_t)(kr + k) * DDIM + nc + c0;
#pragma unroll
        for (int i = 0; i < 4; ++i) {
            float4 v = *(const float4*)(src + i * 4);
            T[k][c0 + i * 4 + 0] = f2bf(v.x);
            T[k][c0 + i * 4 + 1] = f2bf(v.y);
            T[k][c0 + i * 4 + 2] = f2bf(v.z);
            T[k][c0 + i * 4 + 3] = f2bf(v.w);
        }
    }
    __syncthreads();
    {   // store transposed: thread t -> n = nc+(t>>2), k chunk kr+(t&3)*16..+15
        const int n = t >> 2, kc = (t & 3) * 16;
        union { unsigned short u[16]; uint4 v[2]; } o;
#pragma unroll
        for (int i = 0; i < 16; ++i) o.u[i] = T[kc + i][n];
        uint4* dst = (uint4*)(Wt + ((size_t)j << 16)
                              + (size_t)(nc + n) * DDIM + kr + kc);
        dst[0] = o.v[0]; dst[1] = o.v[1];
    }
    // zero stat shards (48 blocks x 256 f32 = 12288) + barrier region (4KB)
    if (b < 48)       stats[b * 256 + t] = 0.f;
    else if (b < 52)  barrier[(b - 48) * 256 + t] = 0u;
}

// ---------------------------------------------------------------------------
// Grid barrier, tree-arrival (R15-proven verbatim): 8 group counters on
// separate 64B lines -> root -> flag; pollers read only the flag with
// s_sleep(8) backoff. Bounded spin: deadlock -> wrong answer, never a hang.
// Phase layout (256 uints): grp g at [g*16], root at [128], flag at [192].
// ---------------------------------------------------------------------------
__device__ __forceinline__ void grid_barrier(unsigned int* base, int phase)
{
    unsigned int* ph = base + phase * 256;
    __syncthreads();   // s_waitcnt vmcnt(0) lgkmcnt(0) + s_barrier (all waves)
    if (threadIdx.x == 0) {
        asm volatile("s_waitcnt vmcnt(0)" ::: "memory");
        unsigned int* gc   = ph + (blockIdx.x >> 6) * 16;   // 8 groups x 64
        unsigned int* root = ph + 128;
        unsigned int* flag = ph + 192;
        bool done = false;
        unsigned int old = __hip_atomic_fetch_add(gc, 1u, __ATOMIC_RELAXED,
                                                  __HIP_MEMORY_SCOPE_AGENT);
        if (old == 63u) {
            unsigned int r = __hip_atomic_fetch_add(root, 1u, __ATOMIC_RELAXED,
                                                    __HIP_MEMORY_SCOPE_AGENT);
            if (r == 7u) {
                __hip_atomic_store(flag, 1u, __ATOMIC_RELAXED,
                                   __HIP_MEMORY_SCOPE_AGENT);
                done = true;
            }
        }
        if (!done) {
            int cap = 2000000;
            while (!__hip_atomic_load(flag, __ATOMIC_RELAXED,
                                      __HIP_MEMORY_SCOPE_AGENT)) {
                __builtin_amdgcn_s_sleep(8);
                if (--cap == 0) break;
            }
        }
    }
    __syncthreads();
}

// ---------------------------------------------------------------------------
// One layer, 8-wave version (R15 core). Block tile 64x256; wave wn owns
// cols wn*32..+31 (acc 4x2 of 16x16x32 MFMAs).
// GATHER: stage A from table (uint4 swizzled writes).
// !GATHER: acc carries y=GELU(prev) across the barrier; finalize stats ->
//   sc/sh, then write AFFINED A panel directly from registers.
// P layout: row r, granule g (8 bf16) at slot g^(r&7) (conflict-free).
// Stats (R15): s1 at statShards[shard*512+col], s2 at +256, shard=blk&7.
// ---------------------------------------------------------------------------
template<int GATHER, int LAST>
__device__ __forceinline__ void layer_step(
    unsigned short* P, float* sc, float* sh,
    const Params& p, floatx4 (&acc)[4][2],
    const unsigned short* Wt, const float* bias,
    const float* statsIn, const float* gma, const float* bta,
    float* statShards)
{
    const int tid  = threadIdx.x;          // 0..511
    const int blk  = blockIdx.x;
    const int wave = tid >> 6;             // 0..7
    const int lane = tid & 63;
    const int quad = lane >> 4;
    const int l15  = lane & 15;
    const int row0 = blk * 64;

    if (GATHER) {
        // ---- stage A from table (thread t: row t>>3, granules (t&7)*4..+3)
        const int r     = tid >> 3;
        const int gbase = (tid & 7) * 4;
        const int src = p.ids[row0 + r];
        const float* tp = p.table + (size_t)src * DDIM + gbase * 8;
#pragma unroll
        for (int j = 0; j < 4; ++j) {
            float4 v0 = *(const float4*)(tp + j * 8);
            float4 v1 = *(const float4*)(tp + j * 8 + 4);
            union { unsigned short u[8]; uint4 v; } o;
            o.u[0]=f2bf(v0.x); o.u[1]=f2bf(v0.y); o.u[2]=f2bf(v0.z); o.u[3]=f2bf(v0.w);
            o.u[4]=f2bf(v1.x); o.u[5]=f2bf(v1.y); o.u[6]=f2bf(v1.z); o.u[7]=f2bf(v1.w);
            const int g = gbase + j;
            *(uint4*)(P + r * 256 + ((g ^ (r & 7)) << 3)) = o.v;
        }
    } else {
        // ---- finalize BN stats of prev layer (threads 0..255 -> col t).
        // AGENT-scope (sc1) loads read at the coherence point (XCD-safe).
        if (tid < 256) {
            float sum = 0.f, sq = 0.f;
#pragma unroll
            for (int s = 0; s < 8; ++s) {
                sum += __hip_atomic_load(&statsIn[s * 512 + tid],
                                         __ATOMIC_RELAXED, __HIP_MEMORY_SCOPE_AGENT);
                sq  += __hip_atomic_load(&statsIn[s * 512 + 256 + tid],
                                         __ATOMIC_RELAXED, __HIP_MEMORY_SCOPE_AGENT);
            }
            const float mu  = sum * (1.f / 32768.f);
            const float var = sq * (1.f / 32768.f) - mu * mu;
            const float scl = rsqrtf(var + 1e-5f) * gma[tid];
            sc[tid] = scl;
            sh[tid] = bta[tid] - mu * scl;
        }
        __syncthreads();   // sc/sh visible before A-writes use them

        // ---- write AFFINED A panel directly from register-carried y ----
#pragma unroll
        for (int mt = 0; mt < 4; ++mt) {
#pragma unroll
            for (int nt = 0; nt < 2; ++nt) {
                const int col = wave * 32 + nt * 16 + l15;
                const float scl = sc[col], shf = sh[col];
                const int gq = col >> 3, c7 = col & 7;
#pragma unroll
                for (int i = 0; i < 4; ++i) {
                    const int r = mt * 16 + quad * 4 + i;
                    const float a = fmaf(acc[mt][nt][i], scl, shf);
                    P[r * 256 + ((gq ^ (r & 7)) << 3) + c7] = f2bf(a);
                }
            }
        }
    }

    float bias_v[2];
#pragma unroll
    for (int nt = 0; nt < 2; ++nt)
        bias_v[nt] = bias[wave * 32 + nt * 16 + l15];

    __syncthreads();   // A panel visible to all waves

#pragma unroll
    for (int i = 0; i < 4; ++i)
#pragma unroll
        for (int j = 0; j < 2; ++j)
            acc[i][j] = floatx4{0.f, 0.f, 0.f, 0.f};

    // ---- K loop: manual 1-deep pipeline; B from global (L2-hot), A LDS ----
    const unsigned short* wb = Wt + (size_t)(wave * 32 + l15) * DDIM + quad * 8;
    short8 bfr[2], bnx[2], af[4], anx[4];
    {
        const int agp = (quad ^ (l15 & 7)) * 8;               // kk = 0
#pragma unroll
        for (int nt = 0; nt < 2; ++nt)
            bfr[nt] = *(const short8*)(wb + (size_t)(nt * 16) * DDIM);
#pragma unroll
        for (int mt = 0; mt < 4; ++mt)
            af[mt] = *(const short8*)(P + (mt * 16 + l15) * 256 + agp);
    }
#pragma unroll
    for (int kk = 0; kk < 8; ++kk) {
        if (kk < 7) {
            const int agp = (((kk + 1) * 4 + quad) ^ (l15 & 7)) * 8;
#pragma unroll
            for (int nt = 0; nt < 2; ++nt)
                bnx[nt] = *(const short8*)(wb + (size_t)(nt * 16) * DDIM
                                           + (kk + 1) * 32);
#pragma unroll
            for (int mt = 0; mt < 4; ++mt)
                anx[mt] = *(const short8*)(P + (mt * 16 + l15) * 256 + agp);
        }
#pragma unroll
        for (int mt = 0; mt < 4; ++mt)
#pragma unroll
            for (int nt = 0; nt < 2; ++nt)
                acc[mt][nt] = __builtin_amdgcn_mfma_f32_16x16x32_bf16(
                    af[mt], bfr[nt], acc[mt][nt], 0, 0, 0);
#pragma unroll
        for (int x = 0; x < 4; ++x) af[x] = anx[x];
#pragma unroll
        for (int x = 0; x < 2; ++x) bfr[x] = bnx[x];
    }

    // ---- epilogue ----
    if (LAST) {
        // bias + GELU -> global f32 out
#pragma unroll
        for (int mt = 0; mt < 4; ++mt)
#pragma unroll
            for (int nt = 0; nt < 2; ++nt) {
                const int col = wave * 32 + nt * 16 + l15;
#pragma unroll
                for (int i = 0; i < 4; ++i) {
                    const int r = mt * 16 + quad * 4 + i;
                    p.out[(size_t)(row0 + r) * DDIM + col] =
                        gelu_fast(acc[mt][nt][i] + bias_v[nt]);
                }
            }
    } else {
        // bias + GELU -> y kept IN acc (carried across the barrier);
        // column stats -> sharded atomics (R15 layout).
        float s1[2] = {0.f, 0.f};
        float s2[2] = {0.f, 0.f};
#pragma unroll
        for (int mt = 0; mt < 4; ++mt)
#pragma unroll
            for (int nt = 0; nt < 2; ++nt)
#pragma unroll
                for (int i = 0; i < 4; ++i) {
                    const float y = gelu_fast(acc[mt][nt][i] + bias_v[nt]);
                    acc[mt][nt][i] = y;
                    s1[nt] += y; s2[nt] += y * y;
                }
#pragma unroll
        for (int nt = 0; nt < 2; ++nt) {   // reduce the 4 quads (same column)
            s1[nt] += __shfl_xor(s1[nt], 16); s1[nt] += __shfl_xor(s1[nt], 32);
            s2[nt] += __shfl_xor(s2[nt], 16); s2[nt] += __shfl_xor(s2[nt], 32);
        }
        float* sb = statShards + (blk & 7) * 512;            // 8-way shard
        if (quad == 0) {
#pragma unroll
            for (int nt = 0; nt < 2; ++nt) {
                const int col = wave * 32 + nt * 16 + l15;
                atomicAdd(&sb[col],       s1[nt]);
                atomicAdd(&sb[256 + col], s2[nt]);
            }
        }
    }
}

// ---------------------------------------------------------------------------
// Fused kernel: L1..L4, tree-barrier separated; y carried in acc across
// barriers. grid 512 x 512thr, 34KB static LDS, launch_bounds(512,4).
// ---------------------------------------------------------------------------
__global__ __launch_bounds__(512, 4) void fused_enc(Params p)
{
    __shared__ alignas(16) unsigned short P[64 * 256];   // 32 KB panel
    __shared__ float sc[256], sh[256];                   // 2 KB

    floatx4 acc[4][2];

    layer_step<1, 0>(P, sc, sh, p, acc, p.Wt,          p.b[0],
                     nullptr,         nullptr, nullptr, p.stats);
    grid_barrier(p.barrier, 0);
    layer_step<0, 0>(P, sc, sh, p, acc, p.Wt + 65536,  p.b[1],
                     p.stats,         p.g[0],  p.be[0], p.stats + 4096);
    grid_barrier(p.barrier, 1);
    layer_step<0, 0>(P, sc, sh, p, acc, p.Wt + 131072, p.b[2],
                     p.stats + 4096,  p.g[1],  p.be[1], p.stats + 8192);
    grid_barrier(p.barrier, 2);
    layer_step<0, 1>(P, sc, sh, p, acc, p.Wt + 196608, p.b[3],
                     p.stats + 8192,  p.g[2],  p.be[2], nullptr);
}

// ---------------------------------------------------------------------------
extern "C" void kernel_launch(void* const* d_in, const int* in_sizes, int n_in,
                              void* d_out, int out_size, void* d_ws, size_t ws_size,
                              hipStream_t stream)
{
    const float* W1 = (const float*)d_in[2];
    const float* W2 = (const float*)d_in[4];
    const float* W3 = (const float*)d_in[6];
    const float* W4 = (const float*)d_in[8];

    Params pp;
    pp.ids   = (const int*)  d_in[0];
    pp.table = (const float*)d_in[1];
    pp.b[0] = (const float*)d_in[3];
    pp.b[1] = (const float*)d_in[5];
    pp.b[2] = (const float*)d_in[7];
    pp.b[3] = (const float*)d_in[9];
    pp.g[0] = (const float*)d_in[10]; pp.be[0] = (const float*)d_in[11];
    pp.g[1] = (const float*)d_in[12]; pp.be[1] = (const float*)d_in[13];
    pp.g[2] = (const float*)d_in[14]; pp.be[2] = (const float*)d_in[15];

    unsigned char* ws = (unsigned char*)d_ws;
    unsigned short* Wt = (unsigned short*)ws;                  // 512 KiB
    float* stats       = (float*)(ws + (size_t)524288);        // 48 KiB
    unsigned int* bar  = (unsigned int*)(ws + (size_t)589824); // 4 KiB

    pp.Wt      = Wt;
    pp.stats   = stats;
    pp.barrier = bar;
    pp.out     = (float*)d_out;

    prep_kernel<<<64, 256, 0, stream>>>(W1, W2, W3, W4, Wt, stats, bar);
    fused_enc<<<dim3(NBLK), dim3(512), 0, stream>>>(pp);
}

// Round 16
// 159.726 us; speedup vs baseline: 1.0524x; 1.0025x over previous
//
#include <hip/hip_runtime.h>
#include <math.h>

// ---------------------------------------------------------------------------
// StatePerturbationEncoder, R24: R23 core + 2-deep B prefetch in the K-loop.
//  R23 post-mortem: 160.13us -- third reproduction of the optimum (+-0.3%).
//  Not at a HW roofline (HBM 8%, Mfma 8%); the one untested lever is B
//  prefetch DEPTH: R20 proved the K-loop is B-latency-bound (~200cyc L2 vs
//  ~60-100cyc cover from the 1-deep pipeline); R18's failure was VGPR
//  budget (64-reg panel), not mechanism. VGPR_Count is 56/128 -> room for
//  a 3-slot (2-deep) B rotation, +8 VGPRs: loads for kk+2 issue before
//  kk's MFMAs, doubling in-flight cover to ~150-200cyc.
//  Everything else byte-identical to R23 (proven 160.0/160.1/160.6us).
// ---------------------------------------------------------------------------

typedef __attribute__((ext_vector_type(8))) short short8;   // 8 x bf16
typedef __attribute__((ext_vector_type(4))) float floatx4;  // MFMA acc

#define DDIM 256
#define NBLK 512

struct Params {
    const int* ids;
    const float* table;
    const float* b[4];
    const float* g[3];
    const float* be[3];
    const unsigned short* Wt;  // ws: 4 * 65536 bf16 (filled by prep)
    float* stats;              // ws: 3 layers x 4096 f32 (8 shards x 512)
    unsigned int* barrier;     // ws: 4KB region (3 phases x 256 uints used)
    float* out;                // d_out f32
};

__device__ __forceinline__ unsigned short f2bf(float f) {
    union { float f; unsigned int u; } v; v.f = f;
    unsigned int r = v.u + 0x7fffu + ((v.u >> 16) & 1u);   // RNE
    return (unsigned short)(r >> 16);
}
__device__ __forceinline__ float bf2f(unsigned short u) {
    union { unsigned int i; float f; } v; v.i = ((unsigned int)u) << 16;
    return v.f;
}
__device__ __forceinline__ float gelu_fast(float x) {
    // tanh-approx GELU, branchless (validated: absmax 0.023 vs 0.076 thr)
    float z = 0.7978845608f * (x + 0.044715f * x * x * x);
    float e = __expf(2.0f * z);
    float th = 1.0f - 2.0f * __builtin_amdgcn_rcpf(1.0f + e);
    return 0.5f * x * (1.0f + th);
}

// ---------------------------------------------------------------------------
// K0: LDS-tiled transpose+cast W -> Wt (bf16 [n][k]); zero stats + barrier.
// 64 blocks: block b -> W[b>>4], 64x64 tile (b&15). (R15-proven verbatim.)
// ---------------------------------------------------------------------------
__global__ __launch_bounds__(256) void prep_kernel(
    const float* __restrict__ W0, const float* __restrict__ W1,
    const float* __restrict__ W2, const float* __restrict__ W3,
    unsigned short* __restrict__ Wt, float* __restrict__ stats,
    unsigned int* __restrict__ barrier)
{
    __shared__ unsigned short T[64][68];
    const int t = threadIdx.x, b = blockIdx.x;     // 64 blocks x 256 thr
    const int j  = b >> 4;
    const int kr = ((b >> 2) & 3) * 64;            // k (row of W) base
    const int nc = (b & 3) * 64;                   // n (col of W) base
    const float* W = (j == 0) ? W0 : (j == 1) ? W1 : (j == 2) ? W2 : W3;

    {   // load: thread t -> k = kr+(t>>2), cols nc+(t&3)*16 .. +15
        const int k = t >> 2, c0 = (t & 3) * 16;
        const float* src = W + (size_t)(kr + k) * DDIM + nc + c0;
#pragma unroll
        for (int i = 0; i < 4; ++i) {
            float4 v = *(const float4*)(src + i * 4);
            T[k][c0 + i * 4 + 0] = f2bf(v.x);
            T[k][c0 + i * 4 + 1] = f2bf(v.y);
            T[k][c0 + i * 4 + 2] = f2bf(v.z);
            T[k][c0 + i * 4 + 3] = f2bf(v.w);
        }
    }
    __syncthreads();
    {   // store transposed: thread t -> n = nc+(t>>2), k chunk kr+(t&3)*16..+15
        const int n = t >> 2, kc = (t & 3) * 16;
        union { unsigned short u[16]; uint4 v[2]; } o;
#pragma unroll
        for (int i = 0; i < 16; ++i) o.u[i] = T[kc + i][n];
        uint4* dst = (uint4*)(Wt + ((size_t)j << 16)
                              + (size_t)(nc + n) * DDIM + kr + kc);
        dst[0] = o.v[0]; dst[1] = o.v[1];
    }
    // zero stat shards (48 blocks x 256 f32 = 12288) + barrier region (4KB)
    if (b < 48)       stats[b * 256 + t] = 0.f;
    else if (b < 52)  barrier[(b - 48) * 256 + t] = 0u;
}

// ---------------------------------------------------------------------------
// Grid barrier, tree-arrival (R15-proven verbatim): 8 group counters on
// separate 64B lines -> root -> flag; pollers read only the flag with
// s_sleep(8) backoff. Bounded spin: deadlock -> wrong answer, never a hang.
// Phase layout (256 uints): grp g at [g*16], root at [128], flag at [192].
// ---------------------------------------------------------------------------
__device__ __forceinline__ void grid_barrier(unsigned int* base, int phase)
{
    unsigned int* ph = base + phase * 256;
    __syncthreads();   // s_waitcnt vmcnt(0) lgkmcnt(0) + s_barrier (all waves)
    if (threadIdx.x == 0) {
        asm volatile("s_waitcnt vmcnt(0)" ::: "memory");
        unsigned int* gc   = ph + (blockIdx.x >> 6) * 16;   // 8 groups x 64
        unsigned int* root = ph + 128;
        unsigned int* flag = ph + 192;
        bool done = false;
        unsigned int old = __hip_atomic_fetch_add(gc, 1u, __ATOMIC_RELAXED,
                                                  __HIP_MEMORY_SCOPE_AGENT);
        if (old == 63u) {
            unsigned int r = __hip_atomic_fetch_add(root, 1u, __ATOMIC_RELAXED,
                                                    __HIP_MEMORY_SCOPE_AGENT);
            if (r == 7u) {
                __hip_atomic_store(flag, 1u, __ATOMIC_RELAXED,
                                   __HIP_MEMORY_SCOPE_AGENT);
                done = true;
            }
        }
        if (!done) {
            int cap = 2000000;
            while (!__hip_atomic_load(flag, __ATOMIC_RELAXED,
                                      __HIP_MEMORY_SCOPE_AGENT)) {
                __builtin_amdgcn_s_sleep(8);
                if (--cap == 0) break;
            }
        }
    }
    __syncthreads();
}

// ---------------------------------------------------------------------------
// One layer, 8-wave version (R23 core; K-loop B now 2-deep). Block tile
// 64x256; wave wn owns cols wn*32..+31 (acc 4x2 of 16x16x32 MFMAs).
// GATHER: stage A from table. !GATHER: acc carries y=GELU(prev) across the
// barrier; finalize stats -> sc/sh; write AFFINED A panel from registers.
// P layout: row r, granule g (8 bf16) at slot g^(r&7) (conflict-free).
// Stats: s1 at statShards[shard*512+col], s2 at +256, shard=blk&7.
// ---------------------------------------------------------------------------
template<int GATHER, int LAST>
__device__ __forceinline__ void layer_step(
    unsigned short* P, float* sc, float* sh,
    const Params& p, floatx4 (&acc)[4][2],
    const unsigned short* Wt, const float* bias,
    const float* statsIn, const float* gma, const float* bta,
    float* statShards)
{
    const int tid  = threadIdx.x;          // 0..511
    const int blk  = blockIdx.x;
    const int wave = tid >> 6;             // 0..7
    const int lane = tid & 63;
    const int quad = lane >> 4;
    const int l15  = lane & 15;
    const int row0 = blk * 64;

    if (GATHER) {
        // ---- stage A from table (thread t: row t>>3, granules (t&7)*4..+3)
        const int r     = tid >> 3;
        const int gbase = (tid & 7) * 4;
        const int src = p.ids[row0 + r];
        const float* tp = p.table + (size_t)src * DDIM + gbase * 8;
#pragma unroll
        for (int j = 0; j < 4; ++j) {
            float4 v0 = *(const float4*)(tp + j * 8);
            float4 v1 = *(const float4*)(tp + j * 8 + 4);
            union { unsigned short u[8]; uint4 v; } o;
            o.u[0]=f2bf(v0.x); o.u[1]=f2bf(v0.y); o.u[2]=f2bf(v0.z); o.u[3]=f2bf(v0.w);
            o.u[4]=f2bf(v1.x); o.u[5]=f2bf(v1.y); o.u[6]=f2bf(v1.z); o.u[7]=f2bf(v1.w);
            const int g = gbase + j;
            *(uint4*)(P + r * 256 + ((g ^ (r & 7)) << 3)) = o.v;
        }
    } else {
        // ---- finalize BN stats of prev layer (threads 0..255 -> col t).
        // AGENT-scope (sc1) loads read at the coherence point (XCD-safe).
        if (tid < 256) {
            float sum = 0.f, sq = 0.f;
#pragma unroll
            for (int s = 0; s < 8; ++s) {
                sum += __hip_atomic_load(&statsIn[s * 512 + tid],
                                         __ATOMIC_RELAXED, __HIP_MEMORY_SCOPE_AGENT);
                sq  += __hip_atomic_load(&statsIn[s * 512 + 256 + tid],
                                         __ATOMIC_RELAXED, __HIP_MEMORY_SCOPE_AGENT);
            }
            const float mu  = sum * (1.f / 32768.f);
            const float var = sq * (1.f / 32768.f) - mu * mu;
            const float scl = rsqrtf(var + 1e-5f) * gma[tid];
            sc[tid] = scl;
            sh[tid] = bta[tid] - mu * scl;
        }
        __syncthreads();   // sc/sh visible before A-writes use them

        // ---- write AFFINED A panel directly from register-carried y ----
#pragma unroll
        for (int mt = 0; mt < 4; ++mt) {
#pragma unroll
            for (int nt = 0; nt < 2; ++nt) {
                const int col = wave * 32 + nt * 16 + l15;
                const float scl = sc[col], shf = sh[col];
                const int gq = col >> 3, c7 = col & 7;
#pragma unroll
                for (int i = 0; i < 4; ++i) {
                    const int r = mt * 16 + quad * 4 + i;
                    const float a = fmaf(acc[mt][nt][i], scl, shf);
                    P[r * 256 + ((gq ^ (r & 7)) << 3) + c7] = f2bf(a);
                }
            }
        }
    }

    float bias_v[2];
#pragma unroll
    for (int nt = 0; nt < 2; ++nt)
        bias_v[nt] = bias[wave * 32 + nt * 16 + l15];

    __syncthreads();   // A panel visible to all waves

#pragma unroll
    for (int i = 0; i < 4; ++i)
#pragma unroll
        for (int j = 0; j < 2; ++j)
            acc[i][j] = floatx4{0.f, 0.f, 0.f, 0.f};

    // ---- K loop: B 2-deep (3-slot rotation, loads issue 2 iters ahead);
    //      A 1-deep from LDS. All indices compile-time (full unroll). ----
    const unsigned short* wb = Wt + (size_t)(wave * 32 + l15) * DDIM + quad * 8;
    short8 bfr[3][2], af[4], anx[4];
    {
#pragma unroll
        for (int kk = 0; kk < 2; ++kk)                       // B kk=0,1
#pragma unroll
            for (int nt = 0; nt < 2; ++nt)
                bfr[kk][nt] = *(const short8*)(wb + (size_t)(nt * 16) * DDIM
                                               + kk * 32);
        const int agp = (quad ^ (l15 & 7)) * 8;              // A kk=0
#pragma unroll
        for (int mt = 0; mt < 4; ++mt)
            af[mt] = *(const short8*)(P + (mt * 16 + l15) * 256 + agp);
    }
#pragma unroll
    for (int kk = 0; kk < 8; ++kk) {
        if (kk < 6) {                                        // B kk+2
#pragma unroll
            for (int nt = 0; nt < 2; ++nt)
                bfr[(kk + 2) % 3][nt] =
                    *(const short8*)(wb + (size_t)(nt * 16) * DDIM
                                     + (kk + 2) * 32);
        }
        if (kk < 7) {                                        // A kk+1
            const int agp = (((kk + 1) * 4 + quad) ^ (l15 & 7)) * 8;
#pragma unroll
            for (int mt = 0; mt < 4; ++mt)
                anx[mt] = *(const short8*)(P + (mt * 16 + l15) * 256 + agp);
        }
#pragma unroll
        for (int mt = 0; mt < 4; ++mt)
#pragma unroll
            for (int nt = 0; nt < 2; ++nt)
                acc[mt][nt] = __builtin_amdgcn_mfma_f32_16x16x32_bf16(
                    af[mt], bfr[kk % 3][nt], acc[mt][nt], 0, 0, 0);
#pragma unroll
        for (int x = 0; x < 4; ++x) af[x] = anx[x];
    }

    // ---- epilogue ----
    if (LAST) {
        // bias + GELU -> global f32 out
#pragma unroll
        for (int mt = 0; mt < 4; ++mt)
#pragma unroll
            for (int nt = 0; nt < 2; ++nt) {
                const int col = wave * 32 + nt * 16 + l15;
#pragma unroll
                for (int i = 0; i < 4; ++i) {
                    const int r = mt * 16 + quad * 4 + i;
                    p.out[(size_t)(row0 + r) * DDIM + col] =
                        gelu_fast(acc[mt][nt][i] + bias_v[nt]);
                }
            }
    } else {
        // bias + GELU -> y kept IN acc (carried across the barrier);
        // column stats -> sharded atomics (R15 layout).
        float s1[2] = {0.f, 0.f};
        float s2[2] = {0.f, 0.f};
#pragma unroll
        for (int mt = 0; mt < 4; ++mt)
#pragma unroll
            for (int nt = 0; nt < 2; ++nt)
#pragma unroll
                for (int i = 0; i < 4; ++i) {
                    const float y = gelu_fast(acc[mt][nt][i] + bias_v[nt]);
                    acc[mt][nt][i] = y;
                    s1[nt] += y; s2[nt] += y * y;
                }
#pragma unroll
        for (int nt = 0; nt < 2; ++nt) {   // reduce the 4 quads (same column)
            s1[nt] += __shfl_xor(s1[nt], 16); s1[nt] += __shfl_xor(s1[nt], 32);
            s2[nt] += __shfl_xor(s2[nt], 16); s2[nt] += __shfl_xor(s2[nt], 32);
        }
        float* sb = statShards + (blk & 7) * 512;            // 8-way shard
        if (quad == 0) {
#pragma unroll
            for (int nt = 0; nt < 2; ++nt) {
                const int col = wave * 32 + nt * 16 + l15;
                atomicAdd(&sb[col],       s1[nt]);
                atomicAdd(&sb[256 + col], s2[nt]);
            }
        }
    }
}

// ---------------------------------------------------------------------------
// Fused kernel: L1..L4, tree-barrier separated; y carried in acc across
// barriers. grid 512 x 512thr, 34KB static LDS, launch_bounds(512,4).
// ---------------------------------------------------------------------------
__global__ __launch_bounds__(512, 4) void fused_enc(Params p)
{
    __shared__ alignas(16) unsigned short P[64 * 256];   // 32 KB panel
    __shared__ float sc[256], sh[256];                   // 2 KB

    floatx4 acc[4][2];

    layer_step<1, 0>(P, sc, sh, p, acc, p.Wt,          p.b[0],
                     nullptr,         nullptr, nullptr, p.stats);
    grid_barrier(p.barrier, 0);
    layer_step<0, 0>(P, sc, sh, p, acc, p.Wt + 65536,  p.b[1],
                     p.stats,         p.g[0],  p.be[0], p.stats + 4096);
    grid_barrier(p.barrier, 1);
    layer_step<0, 0>(P, sc, sh, p, acc, p.Wt + 131072, p.b[2],
                     p.stats + 4096,  p.g[1],  p.be[1], p.stats + 8192);
    grid_barrier(p.barrier, 2);
    layer_step<0, 1>(P, sc, sh, p, acc, p.Wt + 196608, p.b[3],
                     p.stats + 8192,  p.g[2],  p.be[2], nullptr);
}

// ---------------------------------------------------------------------------
extern "C" void kernel_launch(void* const* d_in, const int* in_sizes, int n_in,
                              void* d_out, int out_size, void* d_ws, size_t ws_size,
                              hipStream_t stream)
{
    const float* W1 = (const float*)d_in[2];
    const float* W2 = (const float*)d_in[4];
    const float* W3 = (const float*)d_in[6];
    const float* W4 = (const float*)d_in[8];

    Params pp;
    pp.ids   = (const int*)  d_in[0];
    pp.table = (const float*)d_in[1];
    pp.b[0] = (const float*)d_in[3];
    pp.b[1] = (const float*)d_in[5];
    pp.b[2] = (const float*)d_in[7];
    pp.b[3] = (const float*)d_in[9];
    pp.g[0] = (const float*)d_in[10]; pp.be[0] = (const float*)d_in[11];
    pp.g[1] = (const float*)d_in[12]; pp.be[1] = (const float*)d_in[13];
    pp.g[2] = (const float*)d_in[14]; pp.be[2] = (const float*)d_in[15];

    unsigned char* ws = (unsigned char*)d_ws;
    unsigned short* Wt = (unsigned short*)ws;                  // 512 KiB
    float* stats       = (float*)(ws + (size_t)524288);        // 48 KiB
    unsigned int* bar  = (unsigned int*)(ws + (size_t)589824); // 4 KiB

    pp.Wt      = Wt;
    pp.stats   = stats;
    pp.barrier = bar;
    pp.out     = (float*)d_out;

    prep_kernel<<<64, 256, 0, stream>>>(W1, W2, W3, W4, Wt, stats, bar);
    fused_enc<<<dim3(NBLK), dim3(512), 0, stream>>>(pp);
}